// Round 9
// baseline (396.124 us; speedup 1.0000x reference)
//
#include <hip/hip_runtime.h>

#define NN 50000
#define NE 400000
#define NG 64
#define SCAN_B 196  // ceil(NN/256)

typedef unsigned short u16;
typedef unsigned int u32;
typedef short short8 __attribute__((ext_vector_type(8)));
typedef float floatx4 __attribute__((ext_vector_type(4)));

__device__ __forceinline__ u16 f2bf(float f) {  // RNE
    union { float f; u32 u; } v; v.f = f;
    return (u16)((v.u + 0x7fff + ((v.u >> 16) & 1)) >> 16);
}
__device__ __forceinline__ float bflo(u32 p) { union { u32 u; float f; } v; v.u = p << 16; return v.f; }
__device__ __forceinline__ float bfhi(u32 p) { union { u32 u; float f; } v; v.u = p & 0xffff0000u; return v.f; }

#define GLD16(g, l) __builtin_amdgcn_global_load_lds( \
    (const __attribute__((address_space(1))) void*)(g), \
    (__attribute__((address_space(3))) void*)(l), 16, 0, 0)

// ---- pack weights into GEMM-ready chunk-contiguous layouts ----
// Wt1r[cb][ks][q][c][j]  (cb:2, ks:16, q:4, c:128, j:8), k=ks*32+q*8+j, col=cb*128+c
// Wt2r[q][c][j]          (q:16, c:64, j:8),              k=q*8+j,       col=c
__global__ __launch_bounds__(256) void prepw_k(const float* __restrict__ W1l,
                                               const float* __restrict__ W1r,
                                               const float* __restrict__ W2l,
                                               const float* __restrict__ W2r,
                                               u16* __restrict__ Wt1r,
                                               u16* __restrict__ Wt2r) {
    const int gid = blockIdx.x * 256 + threadIdx.x;  // 139264 total
    if (gid < 131072) {
        const int j = gid & 7, c = (gid >> 3) & 127, q = (gid >> 10) & 3;
        const int ks = (gid >> 12) & 15, cb = gid >> 16;
        const int k = ks * 32 + q * 8 + j;
        const int col = cb * 128 + c;
        const float v = (col < 128) ? W1l[k * 128 + col] : W1r[k * 128 + (col - 128)];
        Wt1r[gid] = f2bf(v);
    } else {
        const int g2 = gid - 131072;  // 8192
        const int j = g2 & 7, c = (g2 >> 3) & 63, q = g2 >> 9;
        const int k = q * 8 + j;
        const float v = (c < 32) ? W2l[k * 32 + c] : W2r[k * 32 + (c - 32)];
        Wt2r[g2] = f2bf(v);
    }
}

// ---------------- GEMM1 (MFMA, barrier-free direct-load): x[NN,512] @ W^T -> y1[NN,256]
// tile 64x128, grid (782,2), 4 waves (2x2 of 32x64). NO LDS, NO barriers:
// A fragments loaded as fp32 direct from x (cast in-reg), B fragments direct from
// packed Wt1r (wave-contiguous 1KB). Compiler pipelines loads across k-steps freely.
__global__ __launch_bounds__(256) void gemm1_mfma(const float* __restrict__ x,
                                                  const u16* __restrict__ Wt,
                                                  u16* __restrict__ y1) {
    const int t = threadIdx.x, wave = t >> 6, lane = t & 63;
    const int row0 = blockIdx.x * 64, cb = blockIdx.y;
    const int wr = wave >> 1, wc = wave & 1;
    const int q4 = lane >> 4, r16 = lane & 15;

    // A row pointers for this lane's two fragments (A[m=r16][k=q4*8+j])
    const float* xpA[2];
#pragma unroll
    for (int i = 0; i < 2; i++) {
        int grow = row0 + wr * 32 + i * 16 + r16;
        if (grow > NN - 1) grow = NN - 1;
        xpA[i] = x + (size_t)grow * 512 + q4 * 8;
    }
    // B base: col = wc*64 + j*16 + r16, plane q4; ks advances 4096 u16, j advances 128 u16
    const u16* bbase = Wt + ((size_t)((cb * 16 * 4 + q4) * 128 + wc * 64 + r16)) * 8;

    floatx4 acc[2][4] = {};
#pragma unroll 2
    for (int ks = 0; ks < 16; ks++) {
        short8 a[2];
#pragma unroll
        for (int i = 0; i < 2; i++) {
            const float4 f0 = *(const float4*)(xpA[i] + ks * 32);
            const float4 f1 = *(const float4*)(xpA[i] + ks * 32 + 4);
            u32 tmp[4];
            tmp[0] = f2bf(f0.x) | ((u32)f2bf(f0.y) << 16);
            tmp[1] = f2bf(f0.z) | ((u32)f2bf(f0.w) << 16);
            tmp[2] = f2bf(f1.x) | ((u32)f2bf(f1.y) << 16);
            tmp[3] = f2bf(f1.z) | ((u32)f2bf(f1.w) << 16);
            a[i] = *(const short8*)tmp;
        }
        short8 b[4];
#pragma unroll
        for (int j = 0; j < 4; j++)
            b[j] = *(const short8*)(bbase + (size_t)ks * 4096 + j * 128);
#pragma unroll
        for (int i = 0; i < 2; i++)
#pragma unroll
            for (int j = 0; j < 4; j++)
                acc[i][j] = __builtin_amdgcn_mfma_f32_16x16x32_bf16(a[i], b[j], acc[i][j], 0, 0, 0);
    }
#pragma unroll
    for (int i = 0; i < 2; i++) {
        const int row = row0 + wr * 32 + i * 16 + q4 * 4;
#pragma unroll
        for (int j = 0; j < 4; j++) {
            const int col = cb * 128 + wc * 64 + j * 16 + r16;
#pragma unroll
            for (int rg = 0; rg < 4; rg++) {
                if (row + rg < NN) y1[(size_t)(row + rg) * 256 + col] = f2bf(acc[i][j][rg]);
            }
        }
    }
}

// ---------------- GEMM2 (MFMA): h1 (y1 cols 128..256) @ Wt2r -> y2[NN,64] fp32 -------
// tile 64x64, grid 782, whole K=128 staged once, 4 waves (2x2 of 32x32).
__global__ __launch_bounds__(256) void gemm2_mfma(const u16* __restrict__ y1,
                                                  const u16* __restrict__ Wt2r,
                                                  float* __restrict__ y2) {
    __shared__ u16 lA[8192];  // [q 0..15][r 0..63] x 8 (16 KB)
    __shared__ u16 lB[8192];  // [q 0..15][c 0..63] x 8 (16 KB)
    const int t = threadIdx.x, wave = t >> 6, lane = t & 63;
    const int row0 = blockIdx.x * 64;
    const int wr = wave >> 1, wc = wave & 1;
    const int q4 = lane >> 4, r16 = lane & 15;
#pragma unroll
    for (int s = 0; s < 4; s++) {
        const int i = s * 256 + t;          // 0..1023
        const int iq = i >> 6, r = i & 63;  // q-chunk, row
        int grow = row0 + r; if (grow > NN - 1) grow = NN - 1;
        GLD16(y1 + (size_t)grow * 256 + 128 + iq * 8, &lA[(iq * 64 + r) * 8]);
    }
#pragma unroll
    for (int s = 0; s < 4; s++) {
        const int qq = wave * 4 + s;
        GLD16(Wt2r + (size_t)(qq * 64) * 8 + (size_t)lane * 8, &lB[qq * 64 * 8]);
    }
    __builtin_amdgcn_s_waitcnt(0);
    __syncthreads();
    floatx4 acc[2][2] = {};
#pragma unroll
    for (int ks = 0; ks < 4; ks++) {
        const int qk = ks * 4 + q4;
        short8 a[2], b[2];
#pragma unroll
        for (int i = 0; i < 2; i++) a[i] = *(const short8*)&lA[(qk * 64 + wr * 32 + i * 16 + r16) * 8];
#pragma unroll
        for (int j = 0; j < 2; j++) b[j] = *(const short8*)&lB[(qk * 64 + wc * 32 + j * 16 + r16) * 8];
#pragma unroll
        for (int i = 0; i < 2; i++)
#pragma unroll
            for (int j = 0; j < 2; j++)
                acc[i][j] = __builtin_amdgcn_mfma_f32_16x16x32_bf16(a[i], b[j], acc[i][j], 0, 0, 0);
    }
#pragma unroll
    for (int i = 0; i < 2; i++) {
        const int row = row0 + wr * 32 + i * 16 + q4 * 4;
#pragma unroll
        for (int j = 0; j < 2; j++) {
            const int col = wc * 32 + j * 16 + r16;
#pragma unroll
            for (int rg = 0; rg < 4; rg++) {
                if (row + rg < NN) y2[(size_t)(row + rg) * 64 + col] = acc[i][j][rg];
            }
        }
    }
}

// ---------------- CSR build ----------------
__global__ void cnt_k(const int* __restrict__ dst, int* __restrict__ cnt) {
    const int e = blockIdx.x * 256 + threadIdx.x;
    if (e < NE) atomicAdd(&cnt[dst[e]], 1);
}

__global__ __launch_bounds__(256) void scan1_k(const int* __restrict__ cnt,
                                               int* __restrict__ rs, int* __restrict__ bsum) {
    __shared__ int sm[256];
    const int t = threadIdx.x, b = blockIdx.x;
    const int idx = b * 256 + t;
    const int v = (idx < NN) ? cnt[idx] : 0;
    sm[t] = v;
    __syncthreads();
#pragma unroll
    for (int off = 1; off < 256; off <<= 1) {
        const int y = (t >= off) ? sm[t - off] : 0;
        __syncthreads();
        sm[t] += y;
        __syncthreads();
    }
    if (idx < NN) rs[idx] = sm[t] - v;
    if (t == 255) bsum[b] = sm[255];
}

__global__ __launch_bounds__(256) void scan2_k(const int* __restrict__ bsum,
                                               int* __restrict__ bpre, int* __restrict__ rs) {
    __shared__ int sm[256];
    const int t = threadIdx.x;
    const int v = (t < SCAN_B) ? bsum[t] : 0;
    sm[t] = v;
    __syncthreads();
#pragma unroll
    for (int off = 1; off < 256; off <<= 1) {
        const int y = (t >= off) ? sm[t - off] : 0;
        __syncthreads();
        sm[t] += y;
        __syncthreads();
    }
    if (t < SCAN_B) bpre[t] = sm[t] - v;
    if (t == 255) rs[NN] = sm[255];
}

__global__ __launch_bounds__(256) void scan3_k(int* __restrict__ rs, const int* __restrict__ bpre,
                                               int* __restrict__ cursor) {
    const int idx = blockIdx.x * 256 + threadIdx.x;
    if (idx < NN) {
        rs[idx] += bpre[blockIdx.x];
        cursor[idx] = 0;
    }
}

__global__ void place_k(const int* __restrict__ src, const int* __restrict__ dst,
                        const int* __restrict__ rs, int* __restrict__ cursor,
                        int* __restrict__ elist) {
    const int e = blockIdx.x * 256 + threadIdx.x;
    if (e < NE) {
        const int d = dst[e];
        const int p = atomicAdd(&cursor[d], 1);
        elist[rs[d] + p] = src[e];
    }
}

// ---------------- gather1: h1 = relu(mean y1l[nbr] + b + y1r) into y1 cols 128..256 ----
__global__ __launch_bounds__(256) void gather1_k(u16* y1, const int* __restrict__ rs,
                                                 const int* __restrict__ elist,
                                                 const float* __restrict__ b1l) {
    const int t = threadIdx.x;
    const int n = blockIdx.x * 4 + (t >> 6);
    const int lane = t & 63;
    const int s0 = rs[n], s1 = rs[n + 1];
    float a0 = 0.f, a1 = 0.f;
    for (int j = s0; j < s1; j++) {
        const int s = elist[j];
        const u32 v = *(const u32*)(y1 + (size_t)s * 256 + lane * 2);
        a0 += bflo(v);
        a1 += bfhi(v);
    }
    const float inv = 1.f / fmaxf((float)(s1 - s0), 1.f);
    u16* hp = y1 + (size_t)n * 256 + 128 + lane * 2;
    const u32 r = *(const u32*)hp;
    const float h0 = fmaxf(fmaf(a0, inv, b1l[lane * 2] + bflo(r)), 0.f);
    const float h1 = fmaxf(fmaf(a1, inv, b1l[lane * 2 + 1] + bfhi(r)), 0.f);
    *(u32*)hp = (u32)f2bf(h0) | ((u32)f2bf(h1) << 16);
}

// ---------------- gather2: h2[NN,32] fp32 = relu(mean y2l[nbr] + b + y2r) --------------
__global__ __launch_bounds__(256) void gather2_k(const float* __restrict__ y2,
                                                 const int* __restrict__ rs,
                                                 const int* __restrict__ elist,
                                                 const float* __restrict__ b2l,
                                                 float* __restrict__ h2) {
    const int t = threadIdx.x;
    const int n = blockIdx.x * 8 + (t >> 5);
    const int lane = t & 31;
    const int s0 = rs[n], s1 = rs[n + 1];
    float a = 0.f;
    for (int j = s0; j < s1; j++) {
        const int s = elist[j];
        a += y2[(size_t)s * 64 + lane];
    }
    const float inv = 1.f / fmaxf((float)(s1 - s0), 1.f);
    h2[(size_t)n * 32 + lane] = fmaxf(fmaf(a, inv, b2l[lane] + y2[(size_t)n * 64 + 32 + lane]), 0.f);
}

__device__ __forceinline__ float leaky(float v) { return v > 0.f ? v : 0.1f * v; }

// ---------------- pool + MLP head, one block per graph ----------------
__global__ __launch_bounds__(256) void poolmlp_k(const float* __restrict__ h2,
                                                 const int* __restrict__ batch,
                                                 const float* __restrict__ Wl1, const float* __restrict__ bl1,
                                                 const float* __restrict__ Wl2, const float* __restrict__ bl2,
                                                 const float* __restrict__ Wd1, const float* __restrict__ bd1,
                                                 const float* __restrict__ Wd2, const float* __restrict__ bd2,
                                                 const float* __restrict__ Wd3, const float* __restrict__ bd3,
                                                 float* __restrict__ out) {
    __shared__ float red[256];
    __shared__ float bufA[32];
    __shared__ float bufB[32];
    const int g = blockIdx.x;
    const int t = threadIdx.x;
    int s, e;
    {
        int lo = 0, hi = NN;
        while (lo < hi) { const int m = (lo + hi) >> 1; if (batch[m] < g) lo = m + 1; else hi = m; }
        s = lo;
        lo = 0; hi = NN;
        while (lo < hi) { const int m = (lo + hi) >> 1; if (batch[m] < g + 1) lo = m + 1; else hi = m; }
        e = lo;
    }
    const int f = t & 31, grp = t >> 5;
    float acc = 0.f;
    for (int n = s + grp; n < e; n += 8) acc += h2[(size_t)n * 32 + f];
    red[t] = acc;
    __syncthreads();
    if (t < 32) {
        float sum = 0.f;
#pragma unroll
        for (int k = 0; k < 8; k++) sum += red[f + 32 * k];
        bufA[f] = sum / fmaxf((float)(e - s), 1.f);
    }
    __syncthreads();
    if (t < 32) {
        float sacc = bl1[t];
#pragma unroll
        for (int k = 0; k < 32; k++) sacc = fmaf(bufA[k], Wl1[k * 32 + t], sacc);
        bufB[t] = fmaxf(sacc, 0.f);
    }
    __syncthreads();
    if (t < 16) {
        float sacc = bl2[t];
#pragma unroll
        for (int k = 0; k < 32; k++) sacc = fmaf(bufB[k], Wl2[k * 16 + t], sacc);
        const float ev = leaky(sacc);
        bufA[t] = ev;
        out[g * 16 + t] = ev;
    }
    __syncthreads();
    if (t < 32) {
        float sacc = bd1[t];
#pragma unroll
        for (int k = 0; k < 16; k++) sacc = fmaf(bufA[k], Wd1[k * 32 + t], sacc);
        bufB[t] = leaky(sacc);
    }
    __syncthreads();
    if (t < 32) {
        float sacc = bd2[t];
#pragma unroll
        for (int k = 0; k < 32; k++) sacc = fmaf(bufB[k], Wd2[k * 32 + t], sacc);
        bufA[t] = leaky(sacc);
    }
    __syncthreads();
    if (t < 50) {
        float sacc = bd3[t];
#pragma unroll
        for (int k = 0; k < 32; k++) sacc = fmaf(bufA[k], Wd3[k * 50 + t], sacc);
        out[1024 + g * 50 + t] = sacc;
    }
}

extern "C" void kernel_launch(void* const* d_in, const int* in_sizes, int n_in,
                              void* d_out, int out_size, void* d_ws, size_t ws_size,
                              hipStream_t stream) {
    const float* x = (const float*)d_in[0];
    const int* ei = (const int*)d_in[1];
    const int* src = ei;
    const int* dst = ei + NE;
    const int* batch = (const int*)d_in[2];
    const float* W1l = (const float*)d_in[3];
    const float* b1l = (const float*)d_in[4];
    const float* W1r = (const float*)d_in[5];
    const float* W2l = (const float*)d_in[6];
    const float* b2l = (const float*)d_in[7];
    const float* W2r = (const float*)d_in[8];
    const float* Wl1 = (const float*)d_in[9];
    const float* bl1 = (const float*)d_in[10];
    const float* Wl2 = (const float*)d_in[11];
    const float* bl2 = (const float*)d_in[12];
    const float* Wd1 = (const float*)d_in[13];
    const float* bd1 = (const float*)d_in[14];
    const float* Wd2 = (const float*)d_in[15];
    const float* bd2 = (const float*)d_in[16];
    const float* Wd3 = (const float*)d_in[17];
    const float* bd3 = (const float*)d_in[18];

    char* W = (char*)d_ws;
    float* y2 = (float*)W;                     // 12.8M
    float* h2 = (float*)(W + 12800000);        // 6.4M
    u16* y1 = (u16*)(W + 51200000);            // 25.6M  [NN,256] bf16; cols 128..256 become h1
    u16* Wt1r = (u16*)(W + 76800000);          // 262144
    u16* Wt2r = (u16*)(W + 77062144);          // 16384
    int* rs = (int*)(W + 77078528);            // NN+1
    int* cursor = (int*)(W + 77278532);        // NN
    int* elist = (int*)(W + 77478532);         // NE
    int* bsum = (int*)(W + 79078532);          // SCAN_B
    int* bpre = (int*)(W + 79079316);          // SCAN_B

    // --- CSR build ---
    hipMemsetAsync(cursor, 0, (size_t)NN * 4, stream);
    cnt_k<<<(NE + 255) / 256, 256, 0, stream>>>(dst, cursor);
    scan1_k<<<SCAN_B, 256, 0, stream>>>(cursor, rs, bsum);
    scan2_k<<<1, 256, 0, stream>>>(bsum, bpre, rs);
    scan3_k<<<SCAN_B, 256, 0, stream>>>(rs, bpre, cursor);  // also zeros cursor
    place_k<<<(NE + 255) / 256, 256, 0, stream>>>(src, dst, rs, cursor, elist);

    // --- weight packing (GEMM-ready layouts) ---
    prepw_k<<<544, 256, 0, stream>>>(W1l, W1r, W2l, W2r, Wt1r, Wt2r);

    // --- layer 1 (cast fused into GEMM, barrier-free) ---
    gemm1_mfma<<<dim3(782, 2), 256, 0, stream>>>(x, Wt1r, y1);
    gather1_k<<<12500, 256, 0, stream>>>(y1, rs, elist, b1l);

    // --- layer 2 ---
    gemm2_mfma<<<782, 256, 0, stream>>>(y1, Wt2r, y2);
    gather2_k<<<6250, 256, 0, stream>>>(y2, rs, elist, b2l, h2);

    // --- pool + MLP head ---
    poolmlp_k<<<NG, 256, 0, stream>>>(h2, batch, Wl1, bl1, Wl2, bl2,
                                      Wd1, bd1, Wd2, bd2, Wd3, bd3, (float*)d_out);
}

// Round 10
// 348.692 us; speedup vs baseline: 1.1360x; 1.1360x over previous
//
#include <hip/hip_runtime.h>

#define NN 50000
#define NE 400000
#define NG 64
#define SCAN_B 196  // ceil(NN/256)

typedef unsigned short u16;
typedef unsigned int u32;
typedef short short8 __attribute__((ext_vector_type(8)));
typedef float floatx4 __attribute__((ext_vector_type(4)));

__device__ __forceinline__ u16 f2bf(float f) {  // RNE
    union { float f; u32 u; } v; v.f = f;
    return (u16)((v.u + 0x7fff + ((v.u >> 16) & 1)) >> 16);
}
__device__ __forceinline__ float bflo(u32 p) { union { u32 u; float f; } v; v.u = p << 16; return v.f; }
__device__ __forceinline__ float bfhi(u32 p) { union { u32 u; float f; } v; v.u = p & 0xffff0000u; return v.f; }

#define GLD16(g, l) __builtin_amdgcn_global_load_lds( \
    (const __attribute__((address_space(1))) void*)(g), \
    (__attribute__((address_space(3))) void*)(l), 16, 0, 0)

// ---- pack weights into GEMM-ready chunk-contiguous layouts ----
// Wt1r[cb][ks8][q8][c:128][j:8]  k=ks*64+q8*8+j, col=cb*128+c   (131072 u16)
// Wt2r[q:16][c:64][j:8]          k=q*8+j,        col=c          (8192 u16)
__global__ __launch_bounds__(256) void prepw_k(const float* __restrict__ W1l,
                                               const float* __restrict__ W1r,
                                               const float* __restrict__ W2l,
                                               const float* __restrict__ W2r,
                                               u16* __restrict__ Wt1r,
                                               u16* __restrict__ Wt2r) {
    const int gid = blockIdx.x * 256 + threadIdx.x;  // 139264 total
    if (gid < 131072) {
        const int j = gid & 7, c = (gid >> 3) & 127, q8 = (gid >> 10) & 7;
        const int ks = (gid >> 13) & 7, cb = gid >> 16;
        const int k = ks * 64 + q8 * 8 + j;
        const int col = cb * 128 + c;
        const float v = (col < 128) ? W1l[k * 128 + col] : W1r[k * 128 + (col - 128)];
        Wt1r[gid] = f2bf(v);
    } else {
        const int g2 = gid - 131072;  // 8192
        const int j = g2 & 7, c = (g2 >> 3) & 63, q = g2 >> 9;
        const int k = q * 8 + j;
        const float v = (c < 32) ? W2l[k * 32 + c] : W2r[k * 32 + (c - 32)];
        Wt2r[g2] = f2bf(v);
    }
}

// ---------------- GEMM1 (MFMA, fused fp32->bf16 cast): x[NN,512] @ W^T -> y1[NN,256] bf16
// tile 64x128, grid (782,2), 4 waves (2x2 of 32x64), BK=64 (8 stages, 2 k-instr per stage).
// A LDS row-major padded (row stride 144B -> frag reads bank-stride 4, free);
// B via GLD16 from repacked Wt1r (contiguous 1KB per (q8,col-half) plane).
__global__ __launch_bounds__(256) void gemm1_mfma(const float* __restrict__ x,
                                                  const u16* __restrict__ Wt,
                                                  u16* __restrict__ y1) {
    __shared__ u16 lA[64 * 72];   // [row 0..63][q8 0..7 x 8 bf16 + 8 pad] (9 KB)
    __shared__ u16 lB[8 * 128 * 8];  // [q8][col 0..127][8] (16 KB)
    const int t = threadIdx.x, wave = t >> 6, lane = t & 63;
    const int row0 = blockIdx.x * 64, cb = blockIdx.y;
    const int wr = wave >> 1, wc = wave & 1;
    const int q4 = lane >> 4, r16 = lane & 15;

    // A staging items: unit = i*256+t -> row = unit>>3 (0..63), sub(q8) = unit&7
    const int arow = t >> 3, asub = t & 7;   // i=0; i=1 adds 32 rows
    int g0 = row0 + arow;      if (g0 > NN - 1) g0 = NN - 1;
    int g1 = row0 + arow + 32; if (g1 > NN - 1) g1 = NN - 1;
    const float* xr0 = x + (size_t)g0 * 512 + asub * 8;
    const float* xr1 = x + (size_t)g1 * 512 + asub * 8;

    floatx4 acc[2][4] = {};
    for (int ks = 0; ks < 8; ks++) {
        // B: 16 segments of 1KB (q8 x col-half); wave w takes 4
#pragma unroll
        for (int s = 0; s < 4; s++) {
            const int seg = wave * 4 + s, q8 = seg >> 1, half = seg & 1;
            const u16* gsrc = Wt + ((size_t)(((cb * 8 + ks) * 8 + q8) * 128 + half * 64)) * 8;
            GLD16(gsrc + (size_t)lane * 8, &lB[(q8 * 128 + half * 64) * 8]);
        }
        // A: 2 units/thread, 8 lanes cover one row's contiguous 256B chunk
        {
            const float* xp = xr0 + ks * 64;
            const float4 f0 = *(const float4*)xp;
            const float4 f1 = *(const float4*)(xp + 4);
            uint4 p;
            p.x = f2bf(f0.x) | ((u32)f2bf(f0.y) << 16);
            p.y = f2bf(f0.z) | ((u32)f2bf(f0.w) << 16);
            p.z = f2bf(f1.x) | ((u32)f2bf(f1.y) << 16);
            p.w = f2bf(f1.z) | ((u32)f2bf(f1.w) << 16);
            *(uint4*)&lA[arow * 72 + asub * 8] = p;
        }
        {
            const float* xp = xr1 + ks * 64;
            const float4 f0 = *(const float4*)xp;
            const float4 f1 = *(const float4*)(xp + 4);
            uint4 p;
            p.x = f2bf(f0.x) | ((u32)f2bf(f0.y) << 16);
            p.y = f2bf(f0.z) | ((u32)f2bf(f0.w) << 16);
            p.z = f2bf(f1.x) | ((u32)f2bf(f1.y) << 16);
            p.w = f2bf(f1.z) | ((u32)f2bf(f1.w) << 16);
            *(uint4*)&lA[(arow + 32) * 72 + asub * 8] = p;
        }
        __builtin_amdgcn_s_waitcnt(0);
        __syncthreads();
#pragma unroll
        for (int kk = 0; kk < 2; kk++) {
            const int q = kk * 4 + q4;
            short8 a[2], b[4];
#pragma unroll
            for (int i = 0; i < 2; i++)
                a[i] = *(const short8*)&lA[(wr * 32 + i * 16 + r16) * 72 + q * 8];
#pragma unroll
            for (int j = 0; j < 4; j++)
                b[j] = *(const short8*)&lB[(q * 128 + wc * 64 + j * 16 + r16) * 8];
#pragma unroll
            for (int i = 0; i < 2; i++)
#pragma unroll
                for (int j = 0; j < 4; j++)
                    acc[i][j] = __builtin_amdgcn_mfma_f32_16x16x32_bf16(a[i], b[j], acc[i][j], 0, 0, 0);
        }
        __syncthreads();
    }
#pragma unroll
    for (int i = 0; i < 2; i++) {
        const int row = row0 + wr * 32 + i * 16 + q4 * 4;
#pragma unroll
        for (int j = 0; j < 4; j++) {
            const int col = cb * 128 + wc * 64 + j * 16 + r16;
#pragma unroll
            for (int rg = 0; rg < 4; rg++) {
                if (row + rg < NN) y1[(size_t)(row + rg) * 256 + col] = f2bf(acc[i][j][rg]);
            }
        }
    }
}

// ---------------- GEMM2 (MFMA): h1 (y1 cols 128..256) @ Wt2r -> y2[NN,64] fp32 -------
// tile 64x64, grid 782, whole K=128 staged once, 4 waves (2x2 of 32x32).
__global__ __launch_bounds__(256) void gemm2_mfma(const u16* __restrict__ y1,
                                                  const u16* __restrict__ Wt2r,
                                                  float* __restrict__ y2) {
    __shared__ u16 lA[8192];  // [q 0..15][r 0..63] x 8 (16 KB)
    __shared__ u16 lB[8192];  // [q 0..15][c 0..63] x 8 (16 KB)
    const int t = threadIdx.x, wave = t >> 6, lane = t & 63;
    const int row0 = blockIdx.x * 64;
    const int wr = wave >> 1, wc = wave & 1;
    const int q4 = lane >> 4, r16 = lane & 15;
#pragma unroll
    for (int s = 0; s < 4; s++) {
        const int i = s * 256 + t;          // 0..1023
        const int iq = i >> 6, r = i & 63;  // q-chunk, row
        int grow = row0 + r; if (grow > NN - 1) grow = NN - 1;
        GLD16(y1 + (size_t)grow * 256 + 128 + iq * 8, &lA[(iq * 64 + r) * 8]);
    }
#pragma unroll
    for (int s = 0; s < 4; s++) {
        const int qq = wave * 4 + s;
        GLD16(Wt2r + (size_t)(qq * 64) * 8 + (size_t)lane * 8, &lB[qq * 64 * 8]);
    }
    __builtin_amdgcn_s_waitcnt(0);
    __syncthreads();
    floatx4 acc[2][2] = {};
#pragma unroll
    for (int ks = 0; ks < 4; ks++) {
        const int qk = ks * 4 + q4;
        short8 a[2], b[2];
#pragma unroll
        for (int i = 0; i < 2; i++) a[i] = *(const short8*)&lA[(qk * 64 + wr * 32 + i * 16 + r16) * 8];
#pragma unroll
        for (int j = 0; j < 2; j++) b[j] = *(const short8*)&lB[(qk * 64 + wc * 32 + j * 16 + r16) * 8];
#pragma unroll
        for (int i = 0; i < 2; i++)
#pragma unroll
            for (int j = 0; j < 2; j++)
                acc[i][j] = __builtin_amdgcn_mfma_f32_16x16x32_bf16(a[i], b[j], acc[i][j], 0, 0, 0);
    }
#pragma unroll
    for (int i = 0; i < 2; i++) {
        const int row = row0 + wr * 32 + i * 16 + q4 * 4;
#pragma unroll
        for (int j = 0; j < 2; j++) {
            const int col = wc * 32 + j * 16 + r16;
#pragma unroll
            for (int rg = 0; rg < 4; rg++) {
                if (row + rg < NN) y2[(size_t)(row + rg) * 64 + col] = acc[i][j][rg];
            }
        }
    }
}

// ---------------- CSR build ----------------
__global__ void cnt_k(const int* __restrict__ dst, int* __restrict__ cnt) {
    const int e = blockIdx.x * 256 + threadIdx.x;
    if (e < NE) atomicAdd(&cnt[dst[e]], 1);
}

__global__ __launch_bounds__(256) void scan1_k(const int* __restrict__ cnt,
                                               int* __restrict__ rs, int* __restrict__ bsum) {
    __shared__ int sm[256];
    const int t = threadIdx.x, b = blockIdx.x;
    const int idx = b * 256 + t;
    const int v = (idx < NN) ? cnt[idx] : 0;
    sm[t] = v;
    __syncthreads();
#pragma unroll
    for (int off = 1; off < 256; off <<= 1) {
        const int y = (t >= off) ? sm[t - off] : 0;
        __syncthreads();
        sm[t] += y;
        __syncthreads();
    }
    if (idx < NN) rs[idx] = sm[t] - v;
    if (t == 255) bsum[b] = sm[255];
}

__global__ __launch_bounds__(256) void scan2_k(const int* __restrict__ bsum,
                                               int* __restrict__ bpre, int* __restrict__ rs) {
    __shared__ int sm[256];
    const int t = threadIdx.x;
    const int v = (t < SCAN_B) ? bsum[t] : 0;
    sm[t] = v;
    __syncthreads();
#pragma unroll
    for (int off = 1; off < 256; off <<= 1) {
        const int y = (t >= off) ? sm[t - off] : 0;
        __syncthreads();
        sm[t] += y;
        __syncthreads();
    }
    if (t < SCAN_B) bpre[t] = sm[t] - v;
    if (t == 255) rs[NN] = sm[255];
}

__global__ __launch_bounds__(256) void scan3_k(int* __restrict__ rs, const int* __restrict__ bpre,
                                               int* __restrict__ cursor) {
    const int idx = blockIdx.x * 256 + threadIdx.x;
    if (idx < NN) {
        rs[idx] += bpre[blockIdx.x];
        cursor[idx] = 0;
    }
}

__global__ void place_k(const int* __restrict__ src, const int* __restrict__ dst,
                        const int* __restrict__ rs, int* __restrict__ cursor,
                        int* __restrict__ elist) {
    const int e = blockIdx.x * 256 + threadIdx.x;
    if (e < NE) {
        const int d = dst[e];
        const int p = atomicAdd(&cursor[d], 1);
        elist[rs[d] + p] = src[e];
    }
}

// ---------------- gather1: h1 = relu(mean y1l[nbr] + b + y1r) into y1 cols 128..256 ----
__global__ __launch_bounds__(256) void gather1_k(u16* y1, const int* __restrict__ rs,
                                                 const int* __restrict__ elist,
                                                 const float* __restrict__ b1l) {
    const int t = threadIdx.x;
    const int n = blockIdx.x * 4 + (t >> 6);
    const int lane = t & 63;
    const int s0 = rs[n], s1 = rs[n + 1];
    float a0 = 0.f, a1 = 0.f;
    int j = s0;
    for (; j + 2 <= s1; j += 2) {
        const int sA = elist[j], sB = elist[j + 1];
        const u32 vA = *(const u32*)(y1 + (size_t)sA * 256 + lane * 2);
        const u32 vB = *(const u32*)(y1 + (size_t)sB * 256 + lane * 2);
        a0 += bflo(vA); a1 += bfhi(vA);
        a0 += bflo(vB); a1 += bfhi(vB);
    }
    if (j < s1) {
        const u32 v = *(const u32*)(y1 + (size_t)elist[j] * 256 + lane * 2);
        a0 += bflo(v); a1 += bfhi(v);
    }
    const float inv = 1.f / fmaxf((float)(s1 - s0), 1.f);
    u16* hp = y1 + (size_t)n * 256 + 128 + lane * 2;
    const u32 r = *(const u32*)hp;
    const float h0 = fmaxf(fmaf(a0, inv, b1l[lane * 2] + bflo(r)), 0.f);
    const float h1 = fmaxf(fmaf(a1, inv, b1l[lane * 2 + 1] + bfhi(r)), 0.f);
    *(u32*)hp = (u32)f2bf(h0) | ((u32)f2bf(h1) << 16);
}

// ---------------- gather2: h2[NN,32] fp32 = relu(mean y2l[nbr] + b + y2r) --------------
__global__ __launch_bounds__(256) void gather2_k(const float* __restrict__ y2,
                                                 const int* __restrict__ rs,
                                                 const int* __restrict__ elist,
                                                 const float* __restrict__ b2l,
                                                 float* __restrict__ h2) {
    const int t = threadIdx.x;
    const int n = blockIdx.x * 8 + (t >> 5);
    const int lane = t & 31;
    const int s0 = rs[n], s1 = rs[n + 1];
    float a = 0.f;
    int j = s0;
    for (; j + 2 <= s1; j += 2) {
        const float vA = y2[(size_t)elist[j] * 64 + lane];
        const float vB = y2[(size_t)elist[j + 1] * 64 + lane];
        a += vA; a += vB;
    }
    if (j < s1) a += y2[(size_t)elist[j] * 64 + lane];
    const float inv = 1.f / fmaxf((float)(s1 - s0), 1.f);
    h2[(size_t)n * 32 + lane] = fmaxf(fmaf(a, inv, b2l[lane] + y2[(size_t)n * 64 + 32 + lane]), 0.f);
}

__device__ __forceinline__ float leaky(float v) { return v > 0.f ? v : 0.1f * v; }

// ---------------- pool + MLP head, one block per graph ----------------
__global__ __launch_bounds__(256) void poolmlp_k(const float* __restrict__ h2,
                                                 const int* __restrict__ batch,
                                                 const float* __restrict__ Wl1, const float* __restrict__ bl1,
                                                 const float* __restrict__ Wl2, const float* __restrict__ bl2,
                                                 const float* __restrict__ Wd1, const float* __restrict__ bd1,
                                                 const float* __restrict__ Wd2, const float* __restrict__ bd2,
                                                 const float* __restrict__ Wd3, const float* __restrict__ bd3,
                                                 float* __restrict__ out) {
    __shared__ float red[256];
    __shared__ float bufA[32];
    __shared__ float bufB[32];
    const int g = blockIdx.x;
    const int t = threadIdx.x;
    int s, e;
    {
        int lo = 0, hi = NN;
        while (lo < hi) { const int m = (lo + hi) >> 1; if (batch[m] < g) lo = m + 1; else hi = m; }
        s = lo;
        lo = 0; hi = NN;
        while (lo < hi) { const int m = (lo + hi) >> 1; if (batch[m] < g + 1) lo = m + 1; else hi = m; }
        e = lo;
    }
    const int f = t & 31, grp = t >> 5;
    float acc = 0.f;
    for (int n = s + grp; n < e; n += 8) acc += h2[(size_t)n * 32 + f];
    red[t] = acc;
    __syncthreads();
    if (t < 32) {
        float sum = 0.f;
#pragma unroll
        for (int k = 0; k < 8; k++) sum += red[f + 32 * k];
        bufA[f] = sum / fmaxf((float)(e - s), 1.f);
    }
    __syncthreads();
    if (t < 32) {
        float sacc = bl1[t];
#pragma unroll
        for (int k = 0; k < 32; k++) sacc = fmaf(bufA[k], Wl1[k * 32 + t], sacc);
        bufB[t] = fmaxf(sacc, 0.f);
    }
    __syncthreads();
    if (t < 16) {
        float sacc = bl2[t];
#pragma unroll
        for (int k = 0; k < 32; k++) sacc = fmaf(bufB[k], Wl2[k * 16 + t], sacc);
        const float ev = leaky(sacc);
        bufA[t] = ev;
        out[g * 16 + t] = ev;
    }
    __syncthreads();
    if (t < 32) {
        float sacc = bd1[t];
#pragma unroll
        for (int k = 0; k < 16; k++) sacc = fmaf(bufA[k], Wd1[k * 32 + t], sacc);
        bufB[t] = leaky(sacc);
    }
    __syncthreads();
    if (t < 32) {
        float sacc = bd2[t];
#pragma unroll
        for (int k = 0; k < 32; k++) sacc = fmaf(bufB[k], Wd2[k * 32 + t], sacc);
        bufA[t] = leaky(sacc);
    }
    __syncthreads();
    if (t < 50) {
        float sacc = bd3[t];
#pragma unroll
        for (int k = 0; k < 32; k++) sacc = fmaf(bufA[k], Wd3[k * 50 + t], sacc);
        out[1024 + g * 50 + t] = sacc;
    }
}

extern "C" void kernel_launch(void* const* d_in, const int* in_sizes, int n_in,
                              void* d_out, int out_size, void* d_ws, size_t ws_size,
                              hipStream_t stream) {
    const float* x = (const float*)d_in[0];
    const int* ei = (const int*)d_in[1];
    const int* src = ei;
    const int* dst = ei + NE;
    const int* batch = (const int*)d_in[2];
    const float* W1l = (const float*)d_in[3];
    const float* b1l = (const float*)d_in[4];
    const float* W1r = (const float*)d_in[5];
    const float* W2l = (const float*)d_in[6];
    const float* b2l = (const float*)d_in[7];
    const float* W2r = (const float*)d_in[8];
    const float* Wl1 = (const float*)d_in[9];
    const float* bl1 = (const float*)d_in[10];
    const float* Wl2 = (const float*)d_in[11];
    const float* bl2 = (const float*)d_in[12];
    const float* Wd1 = (const float*)d_in[13];
    const float* bd1 = (const float*)d_in[14];
    const float* Wd2 = (const float*)d_in[15];
    const float* bd2 = (const float*)d_in[16];
    const float* Wd3 = (const float*)d_in[17];
    const float* bd3 = (const float*)d_in[18];

    char* W = (char*)d_ws;
    float* y2 = (float*)W;                     // 12.8M
    float* h2 = (float*)(W + 12800000);        // 6.4M
    u16* y1 = (u16*)(W + 51200000);            // 25.6M  [NN,256] bf16; cols 128..256 become h1
    u16* Wt1r = (u16*)(W + 76800000);          // 262144
    u16* Wt2r = (u16*)(W + 77062144);          // 16384
    int* rs = (int*)(W + 77078528);            // NN+1
    int* cursor = (int*)(W + 77278532);        // NN
    int* elist = (int*)(W + 77478532);         // NE
    int* bsum = (int*)(W + 79078532);          // SCAN_B
    int* bpre = (int*)(W + 79079316);          // SCAN_B

    // --- CSR build ---
    hipMemsetAsync(cursor, 0, (size_t)NN * 4, stream);
    cnt_k<<<(NE + 255) / 256, 256, 0, stream>>>(dst, cursor);
    scan1_k<<<SCAN_B, 256, 0, stream>>>(cursor, rs, bsum);
    scan2_k<<<1, 256, 0, stream>>>(bsum, bpre, rs);
    scan3_k<<<SCAN_B, 256, 0, stream>>>(rs, bpre, cursor);  // also zeros cursor
    place_k<<<(NE + 255) / 256, 256, 0, stream>>>(src, dst, rs, cursor, elist);

    // --- weight packing (GEMM-ready layouts) ---
    prepw_k<<<544, 256, 0, stream>>>(W1l, W1r, W2l, W2r, Wt1r, Wt2r);

    // --- layer 1 (cast fused into GEMM, BK=64 staged) ---
    gemm1_mfma<<<dim3(782, 2), 256, 0, stream>>>(x, Wt1r, y1);
    gather1_k<<<12500, 256, 0, stream>>>(y1, rs, elist, b1l);

    // --- layer 2 ---
    gemm2_mfma<<<782, 256, 0, stream>>>(y1, Wt2r, y2);
    gather2_k<<<6250, 256, 0, stream>>>(y2, rs, elist, b2l, h2);

    // --- pool + MLP head ---
    poolmlp_k<<<NG, 256, 0, stream>>>(h2, batch, Wl1, bl1, Wl2, bl2,
                                      Wd1, bd1, Wd2, bd2, Wd3, bd3, (float*)d_out);
}